// Round 1
// baseline (4963.710 us; speedup 1.0000x reference)
//
#include <hip/hip_runtime.h>
#include <hip/hip_bf16.h>

// Problem constants (KoopmanKernelSeq2Seq)
#define M_  512
#define L_  16
#define O_  32
#define D_  64
#define B_  16
#define ML  8192          // M_*L_
#define SLOT (B_*ML)      // 131072 floats per scan slot

__device__ __forceinline__ float sqdiff4(const float4& x, const float4& y) {
    float dx = x.x - y.x, dy = x.y - y.y, dz = x.z - y.z, dw = x.w - y.w;
    return dx*dx + dy*dy + dz*dz + dw*dw;
}

static constexpr float GAMMA = 1.0f / 128.0f;          // 1/(2*D)
static constexpr float SCALE = 0.0441941738241592f;    // 512^-0.5

// out0[b*ML + m*L + l] = SCALE * exp(-GAMMA * ||X_m - inp_{b,l}||^2)
__global__ __launch_bounds__(256) void k_out0(const float* __restrict__ inps,
                                              const float* __restrict__ X,
                                              float* __restrict__ out0) {
    int idx = blockIdx.x * 256 + threadIdx.x;          // B*M*L = 131072
    int l = idx & (L_ - 1);
    int m = (idx >> 4) & (M_ - 1);
    int b = idx >> 13;
    const float* xr = X + m * D_;
    const float* yr = inps + (b * L_ + l) * D_;
    float d2 = 0.f;
#pragma unroll
    for (int d = 0; d < D_; d += 4) {
        float4 xv = *(const float4*)(xr + d);
        float4 yv = *(const float4*)(yr + d);
        d2 += sqdiff4(xv, yv);
    }
    out0[idx] = SCALE * expf(-GAMMA * d2);
}

// KY[i*512 + j] = SCALE * exp(-GAMMA * ||Y_i - Y_j||^2)
__global__ __launch_bounds__(256) void k_ky(const float* __restrict__ Y,
                                            float* __restrict__ KY) {
    int idx = blockIdx.x * 256 + threadIdx.x;          // 512*512
    int j = idx & (M_ - 1);
    int i = idx >> 9;
    const float* yi = Y + i * D_;
    const float* yj = Y + j * D_;
    float d2 = 0.f;
#pragma unroll
    for (int d = 0; d < D_; d += 4) {
        float4 a = *(const float4*)(yi + d);
        float4 b = *(const float4*)(yj + d);
        d2 += sqdiff4(a, b);
    }
    KY[idx] = SCALE * expf(-GAMMA * d2);
}

// W[m*64 + a] = sum_j KY[m][j] * Y[j][a]   (KY symmetric)
__global__ __launch_bounds__(256) void k_w(const float* __restrict__ KY,
                                           const float* __restrict__ Y,
                                           float* __restrict__ W) {
    int idx = blockIdx.x * 256 + threadIdx.x;          // 512*64
    int a = idx & (D_ - 1);
    int m = idx >> 6;
    float acc = 0.f;
    for (int j = 0; j < M_; ++j)
        acc = fmaf(KY[m * M_ + j], Y[j * D_ + a], acc);
    W[idx] = acc;
}

// One scan step: out[b][i] = sum_j G[i][j] * carry[b][j]
// One block (256 threads) per row i; all 16 batch rows share the G-row stream.
__global__ __launch_bounds__(256) void k_step(const float* __restrict__ G,
                                              const float* __restrict__ carry,
                                              float* __restrict__ out) {
    const int i = blockIdx.x;
    const float* __restrict__ grow = G + (size_t)i * ML;
    float acc[B_];
#pragma unroll
    for (int b = 0; b < B_; ++b) acc[b] = 0.f;

    for (int j0 = threadIdx.x * 4; j0 < ML; j0 += 256 * 4) {
        float4 g = *(const float4*)(grow + j0);
#pragma unroll
        for (int b = 0; b < B_; ++b) {
            float4 c = *(const float4*)(carry + b * ML + j0);
            acc[b] = fmaf(g.x, c.x,
                     fmaf(g.y, c.y,
                     fmaf(g.z, c.z,
                     fmaf(g.w, c.w, acc[b]))));
        }
    }

    // wave-level reduce (64 lanes), then cross-wave via LDS
#pragma unroll
    for (int b = 0; b < B_; ++b) {
        float v = acc[b];
#pragma unroll
        for (int off = 32; off > 0; off >>= 1) v += __shfl_down(v, off, 64);
        acc[b] = v;
    }
    __shared__ float red[4][B_];
    int lane = threadIdx.x & 63;
    int wv   = threadIdx.x >> 6;
    if (lane == 0) {
#pragma unroll
        for (int b = 0; b < B_; ++b) red[wv][b] = acc[b];
    }
    __syncthreads();
    if (threadIdx.x < B_) {
        float v = red[0][threadIdx.x] + red[1][threadIdx.x] +
                  red[2][threadIdx.x] + red[3][threadIdx.x];
        out[threadIdx.x * ML + i] = v;
    }
}

// out[((b*L+l)*O + o)*D + a] = sum_m W[m][a] * S[o+1][b][m*L + l]
// wave <-> (b,l,o); lane <-> a. S-slot reads are wave-uniform broadcasts.
__global__ __launch_bounds__(256) void k_final(const float* __restrict__ S,
                                               const float* __restrict__ W,
                                               float* __restrict__ out) {
    int t = blockIdx.x * 256 + threadIdx.x;            // 524288
    int a = t & (D_ - 1);
    int w = t >> 6;                                    // (b*L+l)*O + o
    int o = w & (O_ - 1);
    int bl = w >> 5;                                   // b*L + l
    int l = bl & (L_ - 1);
    int b = bl >> 4;
    const float* slot = S + (size_t)(o + 1) * SLOT + b * ML;
    float acc = 0.f;
    for (int m = 0; m < M_; ++m)
        acc = fmaf(slot[m * L_ + l], W[m * D_ + a], acc);
    out[t] = acc;
}

extern "C" void kernel_launch(void* const* d_in, const int* in_sizes, int n_in,
                              void* d_out, int out_size, void* d_ws, size_t ws_size,
                              hipStream_t stream) {
    const float* inps    = (const float*)d_in[0];   // [16,16,64]
    const float* nys_X   = (const float*)d_in[1];   // [512,64]
    const float* nys_Y   = (const float*)d_in[2];   // [512,64]
    const float* koopman = (const float*)d_in[3];   // [8192,8192]
    float* out = (float*)d_out;                     // [16,16,32,64]

    // workspace layout (floats): 33 scan slots | KY | W
    float* S  = (float*)d_ws;                       // 33 * 131072
    float* KY = S + 33 * SLOT;                      // 512*512
    float* W  = KY + M_ * M_;                       // 512*64

    k_out0<<<(B_ * ML) / 256, 256, 0, stream>>>(inps, nys_X, S);
    k_ky<<<(M_ * M_) / 256, 256, 0, stream>>>(nys_Y, KY);
    k_w<<<(M_ * D_) / 256, 256, 0, stream>>>(KY, nys_Y, W);

    for (int o = 1; o <= O_; ++o) {
        k_step<<<ML, 256, 0, stream>>>(koopman, S + (size_t)(o - 1) * SLOT,
                                       S + (size_t)o * SLOT);
    }

    k_final<<<(B_ * L_ * O_ * D_) / 256, 256, 0, stream>>>(S, W, out);
}

// Round 2
// 1283.039 us; speedup vs baseline: 3.8687x; 3.8687x over previous
//
#include <hip/hip_runtime.h>
#include <hip/hip_bf16.h>

// Problem constants (KoopmanKernelSeq2Seq)
#define M_  512
#define L_  16
#define O_  32
#define D_  64
#define B_  16
#define ML  8192          // M_*L_
#define SLOT (B_*ML)      // 131072 elements per scan slot
#define KC  8             // K-chunks per step GEMM
#define KLEN (ML/KC)      // 1024

typedef __attribute__((ext_vector_type(8))) short short8;
typedef __attribute__((ext_vector_type(4))) float f32x4;

static constexpr float GAMMA = 1.0f / 128.0f;          // 1/(2*D)
static constexpr float SCALE = 0.0441941738241592f;    // 512^-0.5

__device__ __forceinline__ float sqdiff4(const float4& x, const float4& y) {
    float dx = x.x - y.x, dy = x.y - y.y, dz = x.z - y.z, dw = x.w - y.w;
    return dx*dx + dy*dy + dz*dz + dw*dw;
}

__device__ __forceinline__ unsigned short f2bf(float x) {   // RNE f32->bf16
    unsigned u = __float_as_uint(x);
    u = (u + 0x7FFFu + ((u >> 16) & 1u)) >> 16;
    return (unsigned short)u;
}

// ---- cast koopman f32 -> bf16 (once) ----
__global__ __launch_bounds__(256) void k_cast(const float* __restrict__ G,
                                              unsigned short* __restrict__ Gb) {
    size_t t = (size_t)blockIdx.x * 256 + threadIdx.x;   // 8M threads, 8 elems each
    const float4* p = (const float4*)(G + t * 8);
    float4 a = p[0], b = p[1];
    union { short8 v; unsigned short u[8]; } o;
    o.u[0] = f2bf(a.x); o.u[1] = f2bf(a.y); o.u[2] = f2bf(a.z); o.u[3] = f2bf(a.w);
    o.u[4] = f2bf(b.x); o.u[5] = f2bf(b.y); o.u[6] = f2bf(b.z); o.u[7] = f2bf(b.w);
    *(short8*)(Gb + t * 8) = o.v;
}

// ---- out0: RBF(nys_X, inps), dual write f32 + bf16 ----
__global__ __launch_bounds__(256) void k_out0_dual(const float* __restrict__ inps,
                                                   const float* __restrict__ X,
                                                   float* __restrict__ S0,
                                                   unsigned short* __restrict__ C0) {
    int idx = blockIdx.x * 256 + threadIdx.x;          // B*M*L = 131072
    int l = idx & (L_ - 1);
    int m = (idx >> 4) & (M_ - 1);
    int b = idx >> 13;
    const float* xr = X + m * D_;
    const float* yr = inps + (b * L_ + l) * D_;
    float d2 = 0.f;
#pragma unroll
    for (int d = 0; d < D_; d += 4) {
        float4 xv = *(const float4*)(xr + d);
        float4 yv = *(const float4*)(yr + d);
        d2 += sqdiff4(xv, yv);
    }
    float v = SCALE * expf(-GAMMA * d2);
    S0[idx] = v;
    C0[idx] = f2bf(v);
}

// f32-only variant (fallback path)
__global__ __launch_bounds__(256) void k_out0(const float* __restrict__ inps,
                                              const float* __restrict__ X,
                                              float* __restrict__ out0) {
    int idx = blockIdx.x * 256 + threadIdx.x;
    int l = idx & (L_ - 1);
    int m = (idx >> 4) & (M_ - 1);
    int b = idx >> 13;
    const float* xr = X + m * D_;
    const float* yr = inps + (b * L_ + l) * D_;
    float d2 = 0.f;
#pragma unroll
    for (int d = 0; d < D_; d += 4) {
        float4 xv = *(const float4*)(xr + d);
        float4 yv = *(const float4*)(yr + d);
        d2 += sqdiff4(xv, yv);
    }
    out0[idx] = SCALE * expf(-GAMMA * d2);
}

// ---- KY = RBF(nys_Y, nys_Y) * scale ----
__global__ __launch_bounds__(256) void k_ky(const float* __restrict__ Y,
                                            float* __restrict__ KY) {
    int idx = blockIdx.x * 256 + threadIdx.x;          // 512*512
    int j = idx & (M_ - 1);
    int i = idx >> 9;
    const float* yi = Y + i * D_;
    const float* yj = Y + j * D_;
    float d2 = 0.f;
#pragma unroll
    for (int d = 0; d < D_; d += 4) {
        float4 a = *(const float4*)(yi + d);
        float4 b = *(const float4*)(yj + d);
        d2 += sqdiff4(a, b);
    }
    KY[idx] = SCALE * expf(-GAMMA * d2);
}

// ---- W[m][a] = sum_j KY[m][j] * Y[j][a] ----
__global__ __launch_bounds__(256) void k_w(const float* __restrict__ KY,
                                           const float* __restrict__ Y,
                                           float* __restrict__ W) {
    int idx = blockIdx.x * 256 + threadIdx.x;          // 512*64
    int a = idx & (D_ - 1);
    int m = idx >> 6;
    float acc = 0.f;
    for (int j = 0; j < M_; ++j)
        acc = fmaf(KY[m * M_ + j], Y[j * D_ + a], acc);
    W[idx] = acc;
}

// ---- one scan step via MFMA: P[kc][i][b] = sum_{j in chunk} G[i][j]*carry[b][j] ----
// wave <-> (m-tile, k-chunk). A = G[16 x 32] tile, B = carry^T[32 x 16].
__global__ __launch_bounds__(256) void k_step_mfma(const unsigned short* __restrict__ Gb,
                                                   const unsigned short* __restrict__ Cin,
                                                   float* __restrict__ P) {
    int wid  = (blockIdx.x << 2) + (threadIdx.x >> 6);   // 4096 waves
    int lane = threadIdx.x & 63;
    int mt = wid >> 3;            // 512 m-tiles
    int kc = wid & (KC - 1);      // 8 k-chunks
    int i0 = mt << 4;
    int r    = lane & 15;         // A row / B col (batch)
    int koff = (lane >> 4) << 3;  // k offset within 32
    const unsigned short* ap = Gb  + (size_t)(i0 + r) * ML + kc * KLEN + koff;
    const unsigned short* bp = Cin + (size_t)r        * ML + kc * KLEN + koff;
    f32x4 acc = {0.f, 0.f, 0.f, 0.f};
#pragma unroll 8
    for (int k = 0; k < KLEN; k += 32) {
        short8 a = *(const short8*)(ap + k);
        short8 b = *(const short8*)(bp + k);
        acc = __builtin_amdgcn_mfma_f32_16x16x32_bf16(a, b, acc, 0, 0, 0);
    }
    // C/D layout: col = lane&15, row = (lane>>4)*4 + reg   [measured m89/m91]
    float* dst = P + (size_t)kc * SLOT;
    int rbase = (lane >> 4) << 2;
#pragma unroll
    for (int q = 0; q < 4; ++q)
        dst[(size_t)(i0 + rbase + q) * 16 + r] = acc[q];
}

// ---- reduce K-chunk partials -> f32 slot + bf16 carry ----
__global__ __launch_bounds__(256) void k_reduce(const float* __restrict__ P,
                                                float* __restrict__ Sout,
                                                unsigned short* __restrict__ Cout) {
    int idx = blockIdx.x * 256 + threadIdx.x;          // 131072
    int j = idx & (ML - 1);
    int b = idx >> 13;
    float s = 0.f;
#pragma unroll
    for (int kc = 0; kc < KC; ++kc)
        s += P[(size_t)kc * SLOT + (size_t)j * 16 + b];
    Sout[idx] = s;          // slot layout [b][j]
    Cout[idx] = f2bf(s);
}

// ---- fallback f32 step (round-1 kernel) ----
__global__ __launch_bounds__(256) void k_step(const float* __restrict__ G,
                                              const float* __restrict__ carry,
                                              float* __restrict__ out) {
    const int i = blockIdx.x;
    const float* __restrict__ grow = G + (size_t)i * ML;
    float acc[B_];
#pragma unroll
    for (int b = 0; b < B_; ++b) acc[b] = 0.f;
    for (int j0 = threadIdx.x * 4; j0 < ML; j0 += 256 * 4) {
        float4 g = *(const float4*)(grow + j0);
#pragma unroll
        for (int b = 0; b < B_; ++b) {
            float4 c = *(const float4*)(carry + b * ML + j0);
            acc[b] = fmaf(g.x, c.x, fmaf(g.y, c.y, fmaf(g.z, c.z, fmaf(g.w, c.w, acc[b]))));
        }
    }
#pragma unroll
    for (int b = 0; b < B_; ++b) {
        float v = acc[b];
#pragma unroll
        for (int off = 32; off > 0; off >>= 1) v += __shfl_down(v, off, 64);
        acc[b] = v;
    }
    __shared__ float red[4][B_];
    int lane = threadIdx.x & 63;
    int wv   = threadIdx.x >> 6;
    if (lane == 0) {
#pragma unroll
        for (int b = 0; b < B_; ++b) red[wv][b] = acc[b];
    }
    __syncthreads();
    if (threadIdx.x < B_) {
        float v = red[0][threadIdx.x] + red[1][threadIdx.x] +
                  red[2][threadIdx.x] + red[3][threadIdx.x];
        out[threadIdx.x * ML + i] = v;
    }
}

// ---- final: out[((b*L+l)*O+o)*D+a] = sum_m W[m][a] * S[o+1][b][m*L+l] ----
__global__ __launch_bounds__(256) void k_final(const float* __restrict__ S,
                                               const float* __restrict__ W,
                                               float* __restrict__ out) {
    int t = blockIdx.x * 256 + threadIdx.x;            // 524288
    int a = t & (D_ - 1);
    int w = t >> 6;
    int o = w & (O_ - 1);
    int bl = w >> 5;
    int l = bl & (L_ - 1);
    int b = bl >> 4;
    const float* slot = S + (size_t)(o + 1) * SLOT + b * ML;
    float acc = 0.f;
    for (int m = 0; m < M_; ++m)
        acc = fmaf(slot[m * L_ + l], W[m * D_ + a], acc);
    out[t] = acc;
}

extern "C" void kernel_launch(void* const* d_in, const int* in_sizes, int n_in,
                              void* d_out, int out_size, void* d_ws, size_t ws_size,
                              hipStream_t stream) {
    const float* inps    = (const float*)d_in[0];   // [16,16,64]
    const float* nys_X   = (const float*)d_in[1];   // [512,64]
    const float* nys_Y   = (const float*)d_in[2];   // [512,64]
    const float* koopman = (const float*)d_in[3];   // [8192,8192]
    float* out = (float*)d_out;                     // [16,16,32,64]

    const size_t GB_BYTES  = (size_t)ML * ML * 2;          // 128 MB
    const size_t S_BYTES   = (size_t)33 * SLOT * 4;        // 17.3 MB
    const size_t CB_BYTES  = (size_t)33 * SLOT * 2;        // 8.65 MB
    const size_t P_BYTES   = (size_t)KC * SLOT * 4;        // 4 MB
    const size_t KY_BYTES  = (size_t)M_ * M_ * 4;
    const size_t W_BYTES   = (size_t)M_ * D_ * 4;
    const size_t NEED_FAST = GB_BYTES + S_BYTES + CB_BYTES + P_BYTES + KY_BYTES + W_BYTES;

    if (ws_size >= NEED_FAST) {
        // ---------------- fast bf16-MFMA path ----------------
        unsigned short* Gb = (unsigned short*)d_ws;
        float*          S  = (float*)((char*)d_ws + GB_BYTES);
        unsigned short* Cb = (unsigned short*)((char*)S + S_BYTES);
        float*          P  = (float*)((char*)Cb + CB_BYTES);
        float*          KY = (float*)((char*)P + P_BYTES);
        float*          W  = KY + M_ * M_;

        k_cast<<<(int)((size_t)ML * ML / 8 / 256), 256, 0, stream>>>(koopman, Gb);
        k_out0_dual<<<SLOT / 256, 256, 0, stream>>>(inps, nys_X, S, Cb);
        k_ky<<<(M_ * M_) / 256, 256, 0, stream>>>(nys_Y, KY);
        k_w<<<(M_ * D_) / 256, 256, 0, stream>>>(KY, nys_Y, W);

        for (int o = 1; o <= O_; ++o) {
            k_step_mfma<<<1024, 256, 0, stream>>>(Gb, Cb + (size_t)(o - 1) * SLOT, P);
            k_reduce<<<SLOT / 256, 256, 0, stream>>>(P, S + (size_t)o * SLOT,
                                                     Cb + (size_t)o * SLOT);
        }
        k_final<<<(B_ * L_ * O_ * D_) / 256, 256, 0, stream>>>(S, W, out);
    } else {
        // ---------------- fallback f32 path (round-1) ----------------
        float* S  = (float*)d_ws;
        float* KY = S + (size_t)33 * SLOT;
        float* W  = KY + M_ * M_;

        k_out0<<<SLOT / 256, 256, 0, stream>>>(inps, nys_X, S);
        k_ky<<<(M_ * M_) / 256, 256, 0, stream>>>(nys_Y, KY);
        k_w<<<(M_ * D_) / 256, 256, 0, stream>>>(KY, nys_Y, W);
        for (int o = 1; o <= O_; ++o)
            k_step<<<ML, 256, 0, stream>>>(koopman, S + (size_t)(o - 1) * SLOT,
                                           S + (size_t)o * SLOT);
        k_final<<<(B_ * L_ * O_ * D_) / 256, 256, 0, stream>>>(S, W, out);
    }
}

// Round 3
// 958.727 us; speedup vs baseline: 5.1774x; 1.3383x over previous
//
#include <hip/hip_runtime.h>
#include <hip/hip_bf16.h>

// Problem constants (KoopmanKernelSeq2Seq)
#define M_  512
#define L_  16
#define O_  32
#define D_  64
#define B_  16
#define ML  8192          // M_*L_
#define SLOT (B_*ML)      // 131072 elements per scan slot

typedef __attribute__((ext_vector_type(8))) short short8;
typedef __attribute__((ext_vector_type(4))) float f32x4;

static constexpr float GAMMA = 1.0f / 128.0f;          // 1/(2*D)
static constexpr float SCALE = 0.0441941738241592f;    // 512^-0.5

__device__ __forceinline__ float sqdiff4(const float4& x, const float4& y) {
    float dx = x.x - y.x, dy = x.y - y.y, dz = x.z - y.z, dw = x.w - y.w;
    return dx*dx + dy*dy + dz*dz + dw*dw;
}

__device__ __forceinline__ unsigned short f2bf(float x) {   // RNE f32->bf16
    unsigned u = __float_as_uint(x);
    u = (u + 0x7FFFu + ((u >> 16) & 1u)) >> 16;
    return (unsigned short)u;
}

// ---- cast koopman f32 -> bf16 (once) ----
__global__ __launch_bounds__(256) void k_cast(const float* __restrict__ G,
                                              unsigned short* __restrict__ Gb) {
    size_t t = (size_t)blockIdx.x * 256 + threadIdx.x;   // 8M threads, 8 elems each
    const float4* p = (const float4*)(G + t * 8);
    float4 a = p[0], b = p[1];
    union { short8 v; unsigned short u[8]; } o;
    o.u[0] = f2bf(a.x); o.u[1] = f2bf(a.y); o.u[2] = f2bf(a.z); o.u[3] = f2bf(a.w);
    o.u[4] = f2bf(b.x); o.u[5] = f2bf(b.y); o.u[6] = f2bf(b.z); o.u[7] = f2bf(b.w);
    *(short8*)(Gb + t * 8) = o.v;
}

// ---- out0: RBF(nys_X, inps), dual write f32 + bf16 ----
__global__ __launch_bounds__(256) void k_out0_dual(const float* __restrict__ inps,
                                                   const float* __restrict__ X,
                                                   float* __restrict__ S0,
                                                   unsigned short* __restrict__ C0) {
    int idx = blockIdx.x * 256 + threadIdx.x;          // B*M*L = 131072
    int l = idx & (L_ - 1);
    int m = (idx >> 4) & (M_ - 1);
    int b = idx >> 13;
    const float* xr = X + m * D_;
    const float* yr = inps + (b * L_ + l) * D_;
    float d2 = 0.f;
#pragma unroll
    for (int d = 0; d < D_; d += 4) {
        float4 xv = *(const float4*)(xr + d);
        float4 yv = *(const float4*)(yr + d);
        d2 += sqdiff4(xv, yv);
    }
    float v = SCALE * expf(-GAMMA * d2);
    S0[idx] = v;
    C0[idx] = f2bf(v);
}

// f32-only variant (fallback path)
__global__ __launch_bounds__(256) void k_out0(const float* __restrict__ inps,
                                              const float* __restrict__ X,
                                              float* __restrict__ out0) {
    int idx = blockIdx.x * 256 + threadIdx.x;
    int l = idx & (L_ - 1);
    int m = (idx >> 4) & (M_ - 1);
    int b = idx >> 13;
    const float* xr = X + m * D_;
    const float* yr = inps + (b * L_ + l) * D_;
    float d2 = 0.f;
#pragma unroll
    for (int d = 0; d < D_; d += 4) {
        float4 xv = *(const float4*)(xr + d);
        float4 yv = *(const float4*)(yr + d);
        d2 += sqdiff4(xv, yv);
    }
    out0[idx] = SCALE * expf(-GAMMA * d2);
}

// ---- KY = RBF(nys_Y, nys_Y) * scale ----
__global__ __launch_bounds__(256) void k_ky(const float* __restrict__ Y,
                                            float* __restrict__ KY) {
    int idx = blockIdx.x * 256 + threadIdx.x;          // 512*512
    int j = idx & (M_ - 1);
    int i = idx >> 9;
    const float* yi = Y + i * D_;
    const float* yj = Y + j * D_;
    float d2 = 0.f;
#pragma unroll
    for (int d = 0; d < D_; d += 4) {
        float4 a = *(const float4*)(yi + d);
        float4 b = *(const float4*)(yj + d);
        d2 += sqdiff4(a, b);
    }
    KY[idx] = SCALE * expf(-GAMMA * d2);
}

// ---- W[m][a] = sum_j KY[m][j] * Y[j][a] ----
__global__ __launch_bounds__(256) void k_w(const float* __restrict__ KY,
                                           const float* __restrict__ Y,
                                           float* __restrict__ W) {
    int idx = blockIdx.x * 256 + threadIdx.x;          // 512*64
    int a = idx & (D_ - 1);
    int m = idx >> 6;
    float acc = 0.f;
    for (int j = 0; j < M_; ++j)
        acc = fmaf(KY[m * M_ + j], Y[j * D_ + a], acc);
    W[idx] = acc;
}

// ---- fused scan step ----
// Block = 8 waves (512 thr), owns rows [i0, i0+32). Wave w = K-chunk
// [w*1024,(w+1)*1024); 2 m-tiles per wave share one B fragment.
// LDS-reduce 8 partials -> f32 slot + bf16 carry.
__global__ __launch_bounds__(512) void k_step_fused(const unsigned short* __restrict__ Gb,
                                                    const unsigned short* __restrict__ Cin,
                                                    float* __restrict__ Sout,
                                                    unsigned short* __restrict__ Cout) {
    const int i0   = blockIdx.x << 5;            // 256 blocks * 32 rows
    const int w    = threadIdx.x >> 6;           // K-chunk 0..7
    const int lane = threadIdx.x & 63;
    const int r    = lane & 15;
    const int koff = (lane >> 4) << 3;
    const size_t kbase = (size_t)w * 1024 + koff;

    const unsigned short* a0 = Gb + (size_t)(i0 + r)      * ML + kbase;
    const unsigned short* a1 = Gb + (size_t)(i0 + 16 + r) * ML + kbase;
    const unsigned short* bp = Cin + (size_t)r * ML + kbase;

    f32x4 acc0 = {0.f, 0.f, 0.f, 0.f};
    f32x4 acc1 = {0.f, 0.f, 0.f, 0.f};
#pragma unroll 4
    for (int k = 0; k < 1024; k += 32) {
        short8 bv = *(const short8*)(bp + k);
        short8 av0 = *(const short8*)(a0 + k);
        short8 av1 = *(const short8*)(a1 + k);
        acc0 = __builtin_amdgcn_mfma_f32_16x16x32_bf16(av0, bv, acc0, 0, 0, 0);
        acc1 = __builtin_amdgcn_mfma_f32_16x16x32_bf16(av1, bv, acc1, 0, 0, 0);
    }

    // C/D layout: col = lane&15, row = (lane>>4)*4 + q
    __shared__ float red[8][512];
    const int rbase = (lane >> 4) << 2;
#pragma unroll
    for (int q = 0; q < 4; ++q) {
        red[w][(rbase + q) * 16 + r]       = acc0[q];
        red[w][256 + (rbase + q) * 16 + r] = acc1[q];
    }
    __syncthreads();

    // thread tid -> (mt = tid>>8, rr = (tid>>4)&15, b = tid&15)
    const int tid = threadIdx.x;
    float s = red[0][tid] + red[1][tid] + red[2][tid] + red[3][tid] +
              red[4][tid] + red[5][tid] + red[6][tid] + red[7][tid];
    const int b = tid & 15;
    const int i = i0 + (tid >> 4);               // (mt*16 + rr)
    Sout[(size_t)b * ML + i] = s;
    Cout[(size_t)b * ML + i] = f2bf(s);
}

// ---- fallback f32 step (round-1 kernel) ----
__global__ __launch_bounds__(256) void k_step(const float* __restrict__ G,
                                              const float* __restrict__ carry,
                                              float* __restrict__ out) {
    const int i = blockIdx.x;
    const float* __restrict__ grow = G + (size_t)i * ML;
    float acc[B_];
#pragma unroll
    for (int b = 0; b < B_; ++b) acc[b] = 0.f;
    for (int j0 = threadIdx.x * 4; j0 < ML; j0 += 256 * 4) {
        float4 g = *(const float4*)(grow + j0);
#pragma unroll
        for (int b = 0; b < B_; ++b) {
            float4 c = *(const float4*)(carry + b * ML + j0);
            acc[b] = fmaf(g.x, c.x, fmaf(g.y, c.y, fmaf(g.z, c.z, fmaf(g.w, c.w, acc[b]))));
        }
    }
#pragma unroll
    for (int b = 0; b < B_; ++b) {
        float v = acc[b];
#pragma unroll
        for (int off = 32; off > 0; off >>= 1) v += __shfl_down(v, off, 64);
        acc[b] = v;
    }
    __shared__ float red2[4][B_];
    int lane = threadIdx.x & 63;
    int wv   = threadIdx.x >> 6;
    if (lane == 0) {
#pragma unroll
        for (int b = 0; b < B_; ++b) red2[wv][b] = acc[b];
    }
    __syncthreads();
    if (threadIdx.x < B_) {
        float v = red2[0][threadIdx.x] + red2[1][threadIdx.x] +
                  red2[2][threadIdx.x] + red2[3][threadIdx.x];
        out[threadIdx.x * ML + i] = v;
    }
}

// ---- final: out[((b*L+l)*O+o)*D+a] = sum_m W[m][a] * S[o+1][b][m*L+l] ----
__global__ __launch_bounds__(256) void k_final(const float* __restrict__ S,
                                               const float* __restrict__ W,
                                               float* __restrict__ out) {
    int t = blockIdx.x * 256 + threadIdx.x;            // 524288
    int a = t & (D_ - 1);
    int w = t >> 6;
    int o = w & (O_ - 1);
    int bl = w >> 5;
    int l = bl & (L_ - 1);
    int b = bl >> 4;
    const float* slot = S + (size_t)(o + 1) * SLOT + b * ML;
    float acc = 0.f;
    for (int m = 0; m < M_; ++m)
        acc = fmaf(slot[m * L_ + l], W[m * D_ + a], acc);
    out[t] = acc;
}

extern "C" void kernel_launch(void* const* d_in, const int* in_sizes, int n_in,
                              void* d_out, int out_size, void* d_ws, size_t ws_size,
                              hipStream_t stream) {
    const float* inps    = (const float*)d_in[0];   // [16,16,64]
    const float* nys_X   = (const float*)d_in[1];   // [512,64]
    const float* nys_Y   = (const float*)d_in[2];   // [512,64]
    const float* koopman = (const float*)d_in[3];   // [8192,8192]
    float* out = (float*)d_out;                     // [16,16,32,64]

    const size_t GB_BYTES  = (size_t)ML * ML * 2;          // 128 MB
    const size_t S_BYTES   = (size_t)33 * SLOT * 4;        // 17.3 MB
    const size_t CB_BYTES  = (size_t)33 * SLOT * 2;        // 8.65 MB
    const size_t KY_BYTES  = (size_t)M_ * M_ * 4;
    const size_t W_BYTES   = (size_t)M_ * D_ * 4;
    const size_t NEED_FAST = GB_BYTES + S_BYTES + CB_BYTES + KY_BYTES + W_BYTES;

    if (ws_size >= NEED_FAST) {
        // ---------------- fast bf16-MFMA path ----------------
        unsigned short* Gb = (unsigned short*)d_ws;
        float*          S  = (float*)((char*)d_ws + GB_BYTES);
        unsigned short* Cb = (unsigned short*)((char*)S + S_BYTES);
        float*          KY = (float*)((char*)Cb + CB_BYTES);
        float*          W  = KY + M_ * M_;

        k_cast<<<(int)((size_t)ML * ML / 8 / 256), 256, 0, stream>>>(koopman, Gb);
        k_out0_dual<<<SLOT / 256, 256, 0, stream>>>(inps, nys_X, S, Cb);
        k_ky<<<(M_ * M_) / 256, 256, 0, stream>>>(nys_Y, KY);
        k_w<<<(M_ * D_) / 256, 256, 0, stream>>>(KY, nys_Y, W);

        for (int o = 1; o <= O_; ++o) {
            k_step_fused<<<256, 512, 0, stream>>>(Gb,
                                                  Cb + (size_t)(o - 1) * SLOT,
                                                  S + (size_t)o * SLOT,
                                                  Cb + (size_t)o * SLOT);
        }
        k_final<<<(B_ * L_ * O_ * D_) / 256, 256, 0, stream>>>(S, W, out);
    } else {
        // ---------------- fallback f32 path (round-1) ----------------
        float* S  = (float*)d_ws;
        float* KY = S + (size_t)33 * SLOT;
        float* W  = KY + M_ * M_;

        k_out0<<<SLOT / 256, 256, 0, stream>>>(inps, nys_X, S);
        k_ky<<<(M_ * M_) / 256, 256, 0, stream>>>(nys_Y, KY);
        k_w<<<(M_ * D_) / 256, 256, 0, stream>>>(KY, nys_Y, W);
        for (int o = 1; o <= O_; ++o)
            k_step<<<ML, 256, 0, stream>>>(koopman, S + (size_t)(o - 1) * SLOT,
                                           S + (size_t)o * SLOT);
        k_final<<<(B_ * L_ * O_ * D_) / 256, 256, 0, stream>>>(S, W, out);
    }
}